// Round 5
// baseline (920.313 us; speedup 1.0000x reference)
//
#include <hip/hip_runtime.h>
#include <math.h>

#define NB 4
#define NH 16
#define TT 2048
#define CC 1024
#define DD 64
#define MM (NB * TT)   // 8192
#define BK 32

typedef __attribute__((ext_vector_type(8))) _Float16 half8;
typedef __attribute__((ext_vector_type(4))) _Float16 half4;
typedef __attribute__((ext_vector_type(4))) float floatx4;

// ---------------------------------------------------------------------------
// async global->LDS, 16B per lane (linear dest = wave-uniform base + lane*16)
// ---------------------------------------------------------------------------
__device__ __forceinline__ void gload16(const _Float16* g, _Float16* l) {
    auto gp = (const __attribute__((address_space(1))) void*)(uintptr_t)g;
    auto lp = (__attribute__((address_space(3))) void*)(uint32_t)(uintptr_t)l;
    __builtin_amdgcn_global_load_lds(gp, lp, 16, 0, 0);
}

// ---------------------------------------------------------------------------
// Elementwise split: x fp32 -> xh + xl (fp16 pair), same [M,K] layout.
// ---------------------------------------------------------------------------
__global__ __launch_bounds__(256) void split_x_kernel(
    const float* __restrict__ x, _Float16* __restrict__ xh,
    _Float16* __restrict__ xl)
{
    size_t i = ((size_t)blockIdx.x * 256 + threadIdx.x) * 4;
    float4 v = *(const float4*)&x[i];
    half4 h, l;
    h.x = (_Float16)v.x; l.x = (_Float16)(v.x - (float)h.x);
    h.y = (_Float16)v.y; l.y = (_Float16)(v.y - (float)h.y);
    h.z = (_Float16)v.z; l.z = (_Float16)(v.z - (float)h.z);
    h.w = (_Float16)v.w; l.w = (_Float16)(v.w - (float)h.w);
    *(half4*)&xh[i] = h;
    *(half4*)&xl[i] = l;
}

// ---------------------------------------------------------------------------
// Transpose + split: W [K,N] fp32 -> WhT + WlT [N,K] fp16 (k-major for MFMA).
// ---------------------------------------------------------------------------
__global__ __launch_bounds__(256) void splitT_w_kernel(
    const float* __restrict__ W, _Float16* __restrict__ WhT,
    _Float16* __restrict__ WlT, int K, int N)
{
    __shared__ float Ls[64][65];
    const int bN = blockIdx.x * 64;
    const int bK = blockIdx.y * 64;
    const int tid = threadIdx.x;
    const int g = tid >> 4, c = tid & 15;

    #pragma unroll
    for (int u = 0; u < 4; u++) {
        int r = u * 16 + g;
        float4 v = *(const float4*)&W[(size_t)(bK + r) * N + bN + c * 4];
        Ls[r][c * 4 + 0] = v.x; Ls[r][c * 4 + 1] = v.y;
        Ls[r][c * 4 + 2] = v.z; Ls[r][c * 4 + 3] = v.w;
    }
    __syncthreads();
    #pragma unroll
    for (int u = 0; u < 4; u++) {
        int n = u * 16 + g;
        half4 h, l;
        float f;
        f = Ls[c * 4 + 0][n]; h.x = (_Float16)f; l.x = (_Float16)(f - (float)h.x);
        f = Ls[c * 4 + 1][n]; h.y = (_Float16)f; l.y = (_Float16)(f - (float)h.y);
        f = Ls[c * 4 + 2][n]; h.z = (_Float16)f; l.z = (_Float16)(f - (float)h.z);
        f = Ls[c * 4 + 3][n]; h.w = (_Float16)f; l.w = (_Float16)(f - (float)h.w);
        size_t o = (size_t)(bN + n) * K + bK + c * 4;
        *(half4*)&WhT[o] = h;
        *(half4*)&WlT[o] = l;
    }
}

// ---------------------------------------------------------------------------
// Split-fp16 MFMA GEMM: C[M,N] = (Ah+Al)[M,K] x (Bh+Bl)^T[N,K] + bias.
// BM=128, BN=256, BK=32; 512 thr = 8 waves (2M x 4N), 64x64 per wave.
// HI tiles staged via global_load_lds (unit-XOR swizzle, conflict-free
// ds_read_b128), double-buffered, 48 KB LDS -> 2 blocks/CU so barrier-drain
// stalls are hidden by the co-resident block. LO fragments read DIRECTLY
// from global (L2/L3-resident panels; 16 rows x 64 contiguous bytes per
// load). MFMA order hi*hi -> hi*lo -> lo*hi gives lo loads issue-to-use
// distance. mode 0: Cout fp32 + bias; mode 1: QKV scatter (Q split fp16
// [b,h,t,d] x0.125; K split fp16 [b,h,t,d]; V fp16 [b,h,d,t]).
// ---------------------------------------------------------------------------
__global__ __launch_bounds__(512, 4) void gemm_ht3_kernel(
    const _Float16* __restrict__ Ah, const _Float16* __restrict__ Al,
    const _Float16* __restrict__ Bh, const _Float16* __restrict__ Bl,
    const float* __restrict__ bias, float* __restrict__ Cout,
    _Float16* __restrict__ outQh, _Float16* __restrict__ outQl,
    _Float16* __restrict__ outKh, _Float16* __restrict__ outKl,
    _Float16* __restrict__ outVt, int N, int K, int nbx, int mode)
{
    __shared__ _Float16 sAh[2][128 * BK];
    __shared__ _Float16 sBh[2][256 * BK];   // 48 KB total

    // XCD-chunked block swizzle (nblk % 8 == 0 for both launches)
    const int nblk = gridDim.x;
    const int id = blockIdx.x;
    const int swzid = (id & 7) * (nblk >> 3) + (id >> 3);
    const int by = swzid / nbx, bx = swzid - by * nbx;
    const int bm = by * 128, bn = bx * 256;

    const int tid = threadIdx.x;
    const int w = tid >> 6, lane = tid & 63;
    const int wm = (w >> 2) * 64, wn = (w & 3) * 64;
    const int fr = lane & 15, g = lane >> 4;

    // staging map: wave w covers 16 rows/issue; lane -> row w*16+(lane>>2),
    // slot lane&3; global unit pre-swizzled so LDS stays linear.
    const int rS = w * 16 + (lane >> 2);
    const int ug = ((lane & 3) ^ ((rS >> 1) & 3)) * 8;   // halfs
    const size_t gA  = (size_t)(bm + rS) * K + ug;
    const size_t gB0 = (size_t)(bn + rS) * K + ug;
    const size_t gB1 = (size_t)(bn + 128 + rS) * K + ug;
    const int ldsW = w * 16 * BK;

    auto stage = [&](int kt, int c) {
        const int k0 = kt * BK;
        gload16(&Ah[gA + k0],  &sAh[c][ldsW]);
        gload16(&Bh[gB0 + k0], &sBh[c][ldsW]);
        gload16(&Bh[gB1 + k0], &sBh[c][128 * BK + ldsW]);
    };

    // hi-frag LDS offsets (swizzled read) + lo-frag global offsets (linear)
    int offA[4], offB[4];
    size_t goA[4], goB[4];
    #pragma unroll
    for (int t = 0; t < 4; t++) {
        const int ra = wm + t * 16 + fr;
        offA[t] = ra * BK + ((g ^ ((ra >> 1) & 3)) << 3);
        goA[t] = (size_t)(bm + ra) * K + (g << 3);
        const int rb = wn + t * 16 + fr;
        offB[t] = rb * BK + ((g ^ ((rb >> 1) & 3)) << 3);
        goB[t] = (size_t)(bn + rb) * K + (g << 3);
    }

    floatx4 acc[4][4];
    #pragma unroll
    for (int i = 0; i < 4; i++)
        #pragma unroll
        for (int j = 0; j < 4; j++)
            acc[i][j] = (floatx4){0.f, 0.f, 0.f, 0.f};

    stage(0, 0);
    stage(1, 1);
    __syncthreads();

    const int NK = K >> 5;
    for (int kt = 0; kt < NK; kt++) {
        const int c = kt & 1;
        const int k0 = kt * BK;
        // lo fragments: direct global (issue first -> latency cover)
        half8 a_l[4], b_l[4];
        #pragma unroll
        for (int t = 0; t < 4; t++) {
            a_l[t] = *(const half8*)&Al[goA[t] + k0];
            b_l[t] = *(const half8*)&Bl[goB[t] + k0];
        }
        // hi fragments: LDS
        half8 a_h[4], b_h[4];
        #pragma unroll
        for (int t = 0; t < 4; t++) {
            a_h[t] = *(const half8*)&sAh[c][offA[t]];
            b_h[t] = *(const half8*)&sBh[c][offB[t]];
        }
        __builtin_amdgcn_s_setprio(1);
        #pragma unroll
        for (int mt = 0; mt < 4; mt++)
            #pragma unroll
            for (int nt = 0; nt < 4; nt++)
                acc[mt][nt] = __builtin_amdgcn_mfma_f32_16x16x32_f16(
                    a_h[mt], b_h[nt], acc[mt][nt], 0, 0, 0);
        #pragma unroll
        for (int mt = 0; mt < 4; mt++)
            #pragma unroll
            for (int nt = 0; nt < 4; nt++)
                acc[mt][nt] = __builtin_amdgcn_mfma_f32_16x16x32_f16(
                    a_h[mt], b_l[nt], acc[mt][nt], 0, 0, 0);
        #pragma unroll
        for (int mt = 0; mt < 4; mt++)
            #pragma unroll
            for (int nt = 0; nt < 4; nt++)
                acc[mt][nt] = __builtin_amdgcn_mfma_f32_16x16x32_f16(
                    a_l[mt], b_h[nt], acc[mt][nt], 0, 0, 0);
        __builtin_amdgcn_s_setprio(0);
        __syncthreads();
        if (kt + 2 < NK) stage(kt + 2, c);
    }

    const int col = lane & 15, row4 = g * 4;
    if (mode == 0) {
        #pragma unroll
        for (int mt = 0; mt < 4; mt++)
            #pragma unroll
            for (int nt = 0; nt < 4; nt++) {
                const int n = bn + wn + nt * 16 + col;
                const float bv = bias[n];
                const int m0 = bm + wm + mt * 16 + row4;
                #pragma unroll
                for (int r = 0; r < 4; r++)
                    Cout[(size_t)(m0 + r) * N + n] = acc[mt][nt][r] + bv;
            }
    } else {
        #pragma unroll
        for (int mt = 0; mt < 4; mt++)
            #pragma unroll
            for (int nt = 0; nt < 4; nt++) {
                const int n = bn + wn + nt * 16 + col;
                const int which = n >> 10;
                const int cc_ = n & 1023;
                const int hh_ = cc_ >> 6, d = cc_ & 63;
                const int m0 = bm + wm + mt * 16 + row4;
                const int b = m0 >> 11, t0 = m0 & 2047;
                const size_t bhx = (size_t)b * NH + hh_;
                const float bv = bias[n];
                if (which == 0) {        // Q: split fp16 [b,h,t,d], x0.125
                    #pragma unroll
                    for (int r = 0; r < 4; r++) {
                        const float qv = (acc[mt][nt][r] + bv) * 0.125f;
                        const _Float16 qh_ = (_Float16)qv;
                        const size_t o = (bhx * TT + t0 + r) * DD + d;
                        outQh[o] = qh_;
                        outQl[o] = (_Float16)(qv - (float)qh_);
                    }
                } else if (which == 1) { // K: split fp16 [b,h,t,d]
                    #pragma unroll
                    for (int r = 0; r < 4; r++) {
                        const float kv = acc[mt][nt][r] + bv;
                        const _Float16 kh_ = (_Float16)kv;
                        const size_t o = (bhx * TT + t0 + r) * DD + d;
                        outKh[o] = kh_;
                        outKl[o] = (_Float16)(kv - (float)kh_);
                    }
                } else {                 // V: fp16 [b,h,d,t]
                    half4 vv;
                    #pragma unroll
                    for (int r = 0; r < 4; r++)
                        vv[r] = (_Float16)(acc[mt][nt][r] + bv);
                    *(half4*)&outVt[(bhx * DD + d) * TT + t0] = vv;
                }
            }
    }
}

// ---------------------------------------------------------------------------
// Sparsemax over D=64, one wave per row t, in-place on split K [b,h,t,d].
// ---------------------------------------------------------------------------
__global__ __launch_bounds__(256) void sparsemax_kernel(
    _Float16* __restrict__ Kh, _Float16* __restrict__ Kl)
{
    const int lane = threadIdx.x & 63;
    const size_t row = (size_t)blockIdx.x * 4 + (threadIdx.x >> 6);
    const size_t off = row * DD + lane;
    float z = (float)Kh[off] + (float)Kl[off];
    float cnt = 0.f, ss = 0.f;
    #pragma unroll
    for (int j = 0; j < 64; j++) {
        float zj = __shfl(z, j, 64);
        if (zj >= z) { cnt += 1.f; ss += zj; }
    }
    float cond = (1.f + cnt * z > ss) ? 1.f : 0.f;
    float rho = cond, S = cond * z;
    #pragma unroll
    for (int o = 32; o; o >>= 1) {
        rho += __shfl_xor(rho, o, 64);
        S   += __shfl_xor(S,   o, 64);
    }
    float tau = (S - 1.f) / rho;
    float outv = fmaxf(z - tau, 0.f);
    _Float16 hh = (_Float16)outv;
    Kh[off] = hh;
    Kl[off] = (_Float16)(outv - (float)hh);
}

// ---------------------------------------------------------------------------
// MFMA flash attention + XSA correction (unchanged from passing round 3).
// ---------------------------------------------------------------------------
__global__ __launch_bounds__(256, 2) void attn_kernel(
    const _Float16* __restrict__ Qh, const _Float16* __restrict__ Ql,
    const _Float16* __restrict__ Kh, const _Float16* __restrict__ Kl,
    const _Float16* __restrict__ Vt,
    _Float16* __restrict__ Yh, _Float16* __restrict__ Yl)
{
    __shared__ _Float16 sKh[2][64 * DD];
    __shared__ _Float16 sKl[2][64 * DD];
    __shared__ _Float16 sV [2][64 * DD];   // [d][kv], swizzled — 48 KB total

    const int tid = threadIdx.x;
    const int w = tid >> 6, lane = tid & 63;
    const int p = blockIdx.x >> 6;       // tile pair
    const int bhid = blockIdx.x & 63;    // blk%8 == bhid%8 -> head-per-XCD
    const int b = bhid >> 4, h = bhid & 15;
    const size_t bh = (size_t)b * NH + h;
    const _Float16* Qhg = Qh + bh * (size_t)TT * DD;
    const _Float16* Qlg = Ql + bh * (size_t)TT * DD;
    const _Float16* Khg = Kh + bh * (size_t)TT * DD;
    const _Float16* Klg = Kl + bh * (size_t)TT * DD;
    const _Float16* Vtg = Vt + bh * (size_t)DD * TT;

    const int qrow = lane & 15;
    const int g = lane >> 4;
    const int swz = qrow & 7;
    const int sr = lane >> 3;            // staging row-in-chunk 0..7
    const int uu = (lane & 7) ^ sr;      // pre-swizzled source 16B-unit

    auto stage = [&](int kt, int buf) {
        const int rb = w * 16;
        #pragma unroll
        for (int i = 0; i < 2; i++) {
            const int rr = rb + i * 8 + sr;
            const size_t ko = (size_t)(kt * 64 + rr) * DD + (uu << 3);
            gload16(&Khg[ko], &sKh[buf][(rb + i * 8) * DD]);
            gload16(&Klg[ko], &sKl[buf][(rb + i * 8) * DD]);
            gload16(&Vtg[(size_t)rr * TT + kt * 64 + (uu << 3)],
                    &sV[buf][(rb + i * 8) * DD]);
        }
    };

    const int qlist[2] = {p, 15 - p};
    int cur = 0;

    for (int qi = 0; qi < 2; qi++) {
        const int qt = qlist[qi];
        const int wq0 = qt * 128 + w * 32;
        const int wqmax = wq0 + 31;
        const int nkv = 2 * qt + 2;

        // Q fragments (B-operand of swapped S^T MFMA), hi+lo
        half8 qfh[2][2], qfl[2][2];
        #pragma unroll
        for (int nq = 0; nq < 2; nq++)
            #pragma unroll
            for (int ks = 0; ks < 2; ks++) {
                const size_t o = (size_t)(wq0 + nq * 16 + qrow) * DD
                               + (g << 3) + (ks << 5);
                qfh[nq][ks] = *(const half8*)&Qhg[o];
                qfl[nq][ks] = *(const half8*)&Qlg[o];
            }

        floatx4 acc[2][4];
        #pragma unroll
        for (int i = 0; i < 2; i++)
            #pragma unroll
            for (int j = 0; j < 4; j++)
                acc[i][j] = (floatx4){0.f, 0.f, 0.f, 0.f};
        float m_i[2] = {-3.0e38f, -3.0e38f};
        float l_i[2] = {0.f, 0.f};

        __syncthreads();
        stage(0, cur);

        for (int kt = 0; kt < nkv; kt++) {
            __syncthreads();               // drains vmcnt: buf[cur] ready
            if (kt + 1 < nkv) stage(kt + 1, cur ^ 1);

            if (kt * 64 <= wqmax) {        // wave not fully masked
                const _Float16* kb = sKh[cur];
                const _Float16* lb = sKl[cur];
                const _Float16* vbp = sV[cur];

                // S^T = K x Q^T (3-term split): D[kv][q]
                floatx4 s[4][2];
                #pragma unroll
                for (int mk = 0; mk < 4; mk++)
                    #pragma unroll
                    for (int nq = 0; nq < 2; nq++)
                        s[mk][nq] = (floatx4){0.f, 0.f, 0.f, 0.f};

                #pragma unroll
                for (int mk = 0; mk < 4; mk++) {
                    #pragma unroll
                    for (int ks = 0; ks < 2; ks++) {
                        const int off = (qrow + mk * 16) * DD
                                      + (((g + (ks << 2)) ^ swz) << 3);
                        const half8 kfh = *(const half8*)&kb[off];
                        const half8 kfl = *(const half8*)&lb[off];
                        #pragma unroll
                        for (int nq = 0; nq < 2; nq++) {
                            s[mk][nq] = __builtin_amdgcn_mfma_f32_16x16x32_f16(
                                kfh, qfh[nq][ks], s[mk][nq], 0, 0, 0);
                            s[mk][nq] = __builtin_amdgcn_mfma_f32_16x16x32_f16(
                                kfh, qfl[nq][ks], s[mk][nq], 0, 0, 0);
                            s[mk][nq] = __builtin_amdgcn_mfma_f32_16x16x32_f16(
                                kfl, qfh[nq][ks], s[mk][nq], 0, 0, 0);
                        }
                    }
                }

                // causal mask (diagonal tiles only)
                if (kt * 64 + 63 > wq0) {
                    #pragma unroll
                    for (int mk = 0; mk < 4; mk++)
                        #pragma unroll
                        for (int nq = 0; nq < 2; nq++)
                            #pragma unroll
                            for (int r = 0; r < 4; r++) {
                                const int kvg = kt * 64 + mk * 16 + (g << 2) + r;
                                const int qg  = wq0 + nq * 16 + qrow;
                                if (kvg > qg) s[mk][nq][r] = -1.0e30f;
                            }
                }

                // online softmax: per lane 16 kv-vals per q-col, 2 shfl hops
                float al_[2];
                #pragma unroll
                for (int nq = 0; nq < 2; nq++) {
                    float mx = s[0][nq][0];
                    #pragma unroll
                    for (int mk = 0; mk < 4; mk++)
                        #pragma unroll
                        for (int r = 0; r < 4; r++)
                            mx = fmaxf(mx, s[mk][nq][r]);
                    mx = fmaxf(mx, __shfl_xor(mx, 16, 64));
                    mx = fmaxf(mx, __shfl_xor(mx, 32, 64));
                    const float mn = fmaxf(m_i[nq], mx);
                    al_[nq] = __expf(m_i[nq] - mn);
                    m_i[nq] = mn;
                    float r0 = 0.f;
                    #pragma unroll
                    for (int mk = 0; mk < 4; mk++)
                        #pragma unroll
                        for (int r = 0; r < 4; r++) {
                            const float pp = __expf(s[mk][nq][r] - mn);
                            s[mk][nq][r] = pp;
                            r0 += pp;
                        }
                    r0 += __shfl_xor(r0, 16, 64);
                    r0 += __shfl_xor(r0, 32, 64);
                    l_i[nq] = l_i[nq] * al_[nq] + r0;
                }

                // rescale acc (alpha broadcast: stats live at lane = q&15)
                #pragma unroll
                for (int mt = 0; mt < 2; mt++)
                    #pragma unroll
                    for (int r = 0; r < 4; r++) {
                        const float aB = __shfl(al_[mt], (g << 2) | r, 64);
                        #pragma unroll
                        for (int nt = 0; nt < 4; nt++)
                            acc[mt][nt][r] *= aB;
                    }

                // P -> split fp16 in registers (already in PV A-frag layout)
                half4 ph[4][2], pl[4][2];
                #pragma unroll
                for (int mk = 0; mk < 4; mk++)
                    #pragma unroll
                    for (int nq = 0; nq < 2; nq++)
                        #pragma unroll
                        for (int r = 0; r < 4; r++) {
                            const float pv = s[mk][nq][r];
                            const _Float16 hh = (_Float16)pv;
                            ph[mk][nq][r] = hh;
                            pl[mk][nq][r] = (_Float16)(pv - (float)hh);
                        }

                // PV: acc[q][d] += P x V  (16x16x16, 2-term P split)
                #pragma unroll
                for (int mk = 0; mk < 4; mk++) {
                    #pragma unroll
                    for (int nt = 0; nt < 4; nt++) {
                        const int d = qrow + nt * 16;
                        const int u = ((mk << 1) | (g >> 1)) ^ swz;
                        const half4 vb = *(const half4*)
                            &vbp[d * DD + (u << 3) + ((g & 1) << 2)];
                        #pragma unroll
                        for (int nq = 0; nq < 2; nq++) {
                            acc[nq][nt] = __builtin_amdgcn_mfma_f32_16x16x16f16(
                                ph[mk][nq], vb, acc[nq][nt], 0, 0, 0);
                            acc[nq][nt] = __builtin_amdgcn_mfma_f32_16x16x16f16(
                                pl[mk][nq], vb, acc[nq][nt], 0, 0, 0);
                        }
                    }
                }
            }
            cur ^= 1;
        }

        // epilogue: normalize, XSA correction, split store
        #pragma unroll
        for (int mt = 0; mt < 2; mt++)
            #pragma unroll
            for (int r = 0; r < 4; r++) {
                const int qg = wq0 + mt * 16 + (g << 2) + r;
                const float invl = 1.0f / __shfl(l_i[mt], (g << 2) | r, 64);
                float y0 = acc[mt][0][r] * invl;
                float y1 = acc[mt][1][r] * invl;
                float y2 = acc[mt][2][r] * invl;
                float y3 = acc[mt][3][r] * invl;
                const float v0 = (float)Vtg[(size_t)qrow * TT + qg];
                const float v1 = (float)Vtg[(size_t)(qrow + 16) * TT + qg];
                const float v2 = (float)Vtg[(size_t)(qrow + 32) * TT + qg];
                const float v3 = (float)Vtg[(size_t)(qrow + 48) * TT + qg];
                float n2 = v0 * v0 + v1 * v1 + v2 * v2 + v3 * v3;
                #pragma unroll
                for (int o = 8; o; o >>= 1) n2 += __shfl_xor(n2, o, 64);
                const float ivn = 1.0f / fmaxf(sqrtf(n2), 1e-12f);
                float coef = y0 * v0 + y1 * v1 + y2 * v2 + y3 * v3;
                #pragma unroll
                for (int o = 8; o; o >>= 1) coef += __shfl_xor(coef, o, 64);
                coef *= ivn * ivn;
                const float o0 = y0 - coef * v0;
                const float o1 = y1 - coef * v1;
                const float o2 = y2 - coef * v2;
                const float o3 = y3 - coef * v3;
                const size_t ob = ((size_t)(b * TT + qg)) * CC + h * DD + qrow;
                _Float16 hh;
                hh = (_Float16)o0; Yh[ob]      = hh; Yl[ob]      = (_Float16)(o0 - (float)hh);
                hh = (_Float16)o1; Yh[ob + 16] = hh; Yl[ob + 16] = (_Float16)(o1 - (float)hh);
                hh = (_Float16)o2; Yh[ob + 32] = hh; Yl[ob + 32] = (_Float16)(o2 - (float)hh);
                hh = (_Float16)o3; Yh[ob + 48] = hh; Yl[ob + 48] = (_Float16)(o3 - (float)hh);
            }
    }
}

// ---------------------------------------------------------------------------
extern "C" void kernel_launch(void* const* d_in, const int* in_sizes, int n_in,
                              void* d_out, int out_size, void* d_ws, size_t ws_size,
                              hipStream_t stream) {
    const float* x      = (const float*)d_in[0];
    const float* W_attn = (const float*)d_in[1];
    const float* b_attn = (const float*)d_in[2];
    const float* W_proj = (const float*)d_in[3];
    const float* b_proj = (const float*)d_in[4];
    float* out = (float*)d_out;

    // workspace layout (124 MiB):
    // [0,16)    xh fp16 (dead after gemm1; reused as Yh)
    // [16,32)   xl fp16 (dead after gemm1; reused as Yl)
    // [32,38)   WhT fp16 ([32,34) reused for W_proj hi)
    // [38,44)   WlT fp16 ([34,36) reused for W_proj lo)
    // [44,60)   Qh fp16 [b,h,t,d] scaled
    // [60,76)   Ql fp16 [b,h,t,d] scaled
    // [76,92)   Kh fp16 [b,h,t,d]
    // [92,108)  Kl fp16 [b,h,t,d]
    // [108,124) Vt fp16 [b,h,d,t]
    char* ws = (char*)d_ws;
    _Float16* xh   = (_Float16*)(ws);
    _Float16* xl   = (_Float16*)(ws + ((size_t)16 << 20));
    _Float16* WhT  = (_Float16*)(ws + ((size_t)32 << 20));
    _Float16* WlT  = (_Float16*)(ws + ((size_t)38 << 20));
    _Float16* Qh_  = (_Float16*)(ws + ((size_t)44 << 20));
    _Float16* Ql_  = (_Float16*)(ws + ((size_t)60 << 20));
    _Float16* Kh_  = (_Float16*)(ws + ((size_t)76 << 20));
    _Float16* Kl_  = (_Float16*)(ws + ((size_t)92 << 20));
    _Float16* Vt_  = (_Float16*)(ws + ((size_t)108 << 20));
    _Float16* Yh   = xh;
    _Float16* Yl   = xl;
    _Float16* WphT = WhT;
    _Float16* WplT = (_Float16*)(ws + ((size_t)34 << 20));

    split_x_kernel<<<(MM * CC) / (256 * 4), 256, 0, stream>>>(x, xh, xl);
    splitT_w_kernel<<<dim3(3 * CC / 64, CC / 64), 256, 0, stream>>>(
        W_attn, WhT, WlT, CC, 3 * CC);
    // QKV GEMM: grid 64 x 12 = 768 blocks
    gemm_ht3_kernel<<<dim3((MM / 128) * (3 * CC / 256)), 512, 0, stream>>>(
        xh, xl, WhT, WlT, b_attn, nullptr,
        Qh_, Ql_, Kh_, Kl_, Vt_, 3 * CC, CC, 3 * CC / 256, 1);
    sparsemax_kernel<<<dim3((NB * NH * TT) / 4), 256, 0, stream>>>(Kh_, Kl_);
    attn_kernel<<<dim3(512), 256, 0, stream>>>(Qh_, Ql_, Kh_, Kl_, Vt_, Yh, Yl);
    splitT_w_kernel<<<dim3(CC / 64, CC / 64), 256, 0, stream>>>(
        W_proj, WphT, WplT, CC, CC);
    // proj GEMM: grid 64 x 4 = 256 blocks
    gemm_ht3_kernel<<<dim3((MM / 128) * (CC / 256)), 512, 0, stream>>>(
        Yh, Yl, WphT, WplT, b_proj, out,
        nullptr, nullptr, nullptr, nullptr, nullptr, CC, CC, CC / 256, 0);
}

// Round 6
// 527.058 us; speedup vs baseline: 1.7461x; 1.7461x over previous
//
#include <hip/hip_runtime.h>
#include <math.h>

#define NB 4
#define NH 16
#define TT 2048
#define CC 1024
#define DD 64
#define MM (NB * TT)   // 8192
#define BK 32

typedef __attribute__((ext_vector_type(8))) _Float16 half8;
typedef __attribute__((ext_vector_type(4))) _Float16 half4;
typedef __attribute__((ext_vector_type(4))) float floatx4;

// ---------------------------------------------------------------------------
// async global->LDS, 16B per lane (linear dest = wave-uniform base + lane*16)
// ---------------------------------------------------------------------------
__device__ __forceinline__ void gload16(const _Float16* g, _Float16* l) {
    auto gp = (const __attribute__((address_space(1))) void*)(uintptr_t)g;
    auto lp = (__attribute__((address_space(3))) void*)(uint32_t)(uintptr_t)l;
    __builtin_amdgcn_global_load_lds(gp, lp, 16, 0, 0);
}

// inline-asm LDS read: opaque to the compiler's waitcnt/alias pass, so no
// conservative vmcnt(0) drain is inserted between global_load_lds (other
// buffers) and these reads. MUST be followed by the lgkm fence before use.
__device__ __forceinline__ half8 lds_read_b128(uint32_t addr) {
    floatx4 r;
    asm volatile("ds_read_b128 %0, %1" : "=v"(r) : "v"(addr));
    return __builtin_bit_cast(half8, r);
}
__device__ __forceinline__ void lgkm_fence() {
    asm volatile("s_waitcnt lgkmcnt(0)" ::: "memory");
    __builtin_amdgcn_sched_barrier(0);
}

// ---------------------------------------------------------------------------
// Elementwise split: x fp32 -> xh + xl (fp16 pair), same [M,K] layout.
// ---------------------------------------------------------------------------
__global__ __launch_bounds__(256) void split_x_kernel(
    const float* __restrict__ x, _Float16* __restrict__ xh,
    _Float16* __restrict__ xl)
{
    size_t i = ((size_t)blockIdx.x * 256 + threadIdx.x) * 4;
    float4 v = *(const float4*)&x[i];
    half4 h, l;
    h.x = (_Float16)v.x; l.x = (_Float16)(v.x - (float)h.x);
    h.y = (_Float16)v.y; l.y = (_Float16)(v.y - (float)h.y);
    h.z = (_Float16)v.z; l.z = (_Float16)(v.z - (float)h.z);
    h.w = (_Float16)v.w; l.w = (_Float16)(v.w - (float)h.w);
    *(half4*)&xh[i] = h;
    *(half4*)&xl[i] = l;
}

// ---------------------------------------------------------------------------
// Transpose + split: W [K,N] fp32 -> WhT + WlT [N,K] fp16 (k-major for MFMA).
// ---------------------------------------------------------------------------
__global__ __launch_bounds__(256) void splitT_w_kernel(
    const float* __restrict__ W, _Float16* __restrict__ WhT,
    _Float16* __restrict__ WlT, int K, int N)
{
    __shared__ float Ls[64][65];
    const int bN = blockIdx.x * 64;
    const int bK = blockIdx.y * 64;
    const int tid = threadIdx.x;
    const int g = tid >> 4, c = tid & 15;

    #pragma unroll
    for (int u = 0; u < 4; u++) {
        int r = u * 16 + g;
        float4 v = *(const float4*)&W[(size_t)(bK + r) * N + bN + c * 4];
        Ls[r][c * 4 + 0] = v.x; Ls[r][c * 4 + 1] = v.y;
        Ls[r][c * 4 + 2] = v.z; Ls[r][c * 4 + 3] = v.w;
    }
    __syncthreads();
    #pragma unroll
    for (int u = 0; u < 4; u++) {
        int n = u * 16 + g;
        half4 h, l;
        float f;
        f = Ls[c * 4 + 0][n]; h.x = (_Float16)f; l.x = (_Float16)(f - (float)h.x);
        f = Ls[c * 4 + 1][n]; h.y = (_Float16)f; l.y = (_Float16)(f - (float)h.y);
        f = Ls[c * 4 + 2][n]; h.z = (_Float16)f; l.z = (_Float16)(f - (float)h.z);
        f = Ls[c * 4 + 3][n]; h.w = (_Float16)f; l.w = (_Float16)(f - (float)h.w);
        size_t o = (size_t)(bN + n) * K + bK + c * 4;
        *(half4*)&WhT[o] = h;
        *(half4*)&WlT[o] = l;
    }
}

// ---------------------------------------------------------------------------
// Split-fp16 MFMA GEMM: C[M,N] = (Ah+Al)[M,K] x (Bh+Bl)^T[N,K] + bias.
// BM=128, BN=256, BK=32; 512 thr = 8 waves (2M x 4N), 64x64 per wave.
// Staging: global_load_lds, unit-XOR swizzle, 3 buffers (144 KB).
// Counted-vmcnt schedule per K-step (buf b = kt%3):
//   asm ds_read x16 (opaque: no compiler drain) ; lgkmcnt(0)
//   24 MFMA (nt 0-1) ; s_barrier          // all waves' reads of buf done
//   stage(kt+3 -> buf b)                  // overwrite freed buffer
//   24 MFMA (nt 2-3) ; vmcnt(12)          // retire stage(kt+1) ONLY
//   s_barrier                             // kt+2/kt+3 stay in flight
// Issue->deadline for a stage ~2.3 K-steps (~1100 cyc) > HBM ~900 cyc.
// mode 0: Cout fp32 + bias; mode 1: QKV scatter (Q split fp16 [b,h,t,d]
// x0.125; K split fp16 [b,h,t,d]; V fp16 [b,h,d,t]).
// ---------------------------------------------------------------------------
__global__ __launch_bounds__(512, 2) void gemm_ht3_kernel(
    const _Float16* __restrict__ Ah, const _Float16* __restrict__ Al,
    const _Float16* __restrict__ Bh, const _Float16* __restrict__ Bl,
    const float* __restrict__ bias, float* __restrict__ Cout,
    _Float16* __restrict__ outQh, _Float16* __restrict__ outQl,
    _Float16* __restrict__ outKh, _Float16* __restrict__ outKl,
    _Float16* __restrict__ outVt, int N, int K, int nbx, int mode)
{
    __shared__ _Float16 sAh[3][128 * BK], sAl[3][128 * BK];
    __shared__ _Float16 sBh[3][256 * BK], sBl[3][256 * BK];   // 144 KB

    // XCD-chunked block swizzle (nblk % 8 == 0 for both launches)
    const int nblk = gridDim.x;
    const int id = blockIdx.x;
    const int swzid = (id & 7) * (nblk >> 3) + (id >> 3);
    const int by = swzid / nbx, bx = swzid - by * nbx;
    const int bm = by * 128, bn = bx * 256;

    const int tid = threadIdx.x;
    const int w = tid >> 6, lane = tid & 63;
    const int wm = (w >> 2) * 64, wn = (w & 3) * 64;
    const int fr = lane & 15, g = lane >> 4;

    // staging map: wave w covers 16 rows/issue; lane -> row w*16+(lane>>2),
    // slot lane&3; global unit pre-swizzled so LDS stays linear.
    const int rS = w * 16 + (lane >> 2);
    const int ug = ((lane & 3) ^ ((rS >> 1) & 3)) * 8;   // halfs
    const size_t gA  = (size_t)(bm + rS) * K + ug;
    const size_t gB0 = (size_t)(bn + rS) * K + ug;
    const size_t gB1 = (size_t)(bn + 128 + rS) * K + ug;
    const int ldsW = w * 16 * BK;

    auto stage = [&](int kt, int c) {
        const int k0 = kt * BK;
        gload16(&Ah[gA + k0],  &sAh[c][ldsW]);
        gload16(&Al[gA + k0],  &sAl[c][ldsW]);
        gload16(&Bh[gB0 + k0], &sBh[c][ldsW]);
        gload16(&Bl[gB0 + k0], &sBl[c][ldsW]);
        gload16(&Bh[gB1 + k0], &sBh[c][128 * BK + ldsW]);
        gload16(&Bl[gB1 + k0], &sBl[c][128 * BK + ldsW]);
    };

    // fragment LDS byte offsets (swizzled read side), loop-invariant
    uint32_t offA[4], offB[4];
    #pragma unroll
    for (int t = 0; t < 4; t++) {
        const int ra = wm + t * 16 + fr;
        offA[t] = (uint32_t)(ra * BK + ((g ^ ((ra >> 1) & 3)) << 3)) * 2;
        const int rb = wn + t * 16 + fr;
        offB[t] = (uint32_t)(rb * BK + ((g ^ ((rb >> 1) & 3)) << 3)) * 2;
    }

    floatx4 acc[4][4];
    #pragma unroll
    for (int i = 0; i < 4; i++)
        #pragma unroll
        for (int j = 0; j < 4; j++)
            acc[i][j] = (floatx4){0.f, 0.f, 0.f, 0.f};

    stage(0, 0);
    stage(1, 1);
    stage(2, 2);
    asm volatile("s_waitcnt vmcnt(12)" ::: "memory");   // stage(0) landed
    __builtin_amdgcn_sched_barrier(0);
    __builtin_amdgcn_s_barrier();

    const int NK = K >> 5;
    int b3 = 0;                         // kt % 3
    for (int kt = 0; kt < NK; kt++) {
        const uint32_t aAh = (uint32_t)(uintptr_t)&sAh[b3][0];
        const uint32_t aAl = (uint32_t)(uintptr_t)&sAl[b3][0];
        const uint32_t aBh = (uint32_t)(uintptr_t)&sBh[b3][0];
        const uint32_t aBl = (uint32_t)(uintptr_t)&sBl[b3][0];
        half8 a_h[4], a_l[4], b_h[4], b_l[4];
        #pragma unroll
        for (int t = 0; t < 4; t++) {
            a_h[t] = lds_read_b128(aAh + offA[t]);
            a_l[t] = lds_read_b128(aAl + offA[t]);
            b_h[t] = lds_read_b128(aBh + offB[t]);
            b_l[t] = lds_read_b128(aBl + offB[t]);
        }
        lgkm_fence();                    // reads in regs (rule #18)

        __builtin_amdgcn_s_setprio(1);
        #pragma unroll
        for (int mt = 0; mt < 4; mt++)
            #pragma unroll
            for (int nt = 0; nt < 2; nt++) {
                acc[mt][nt] = __builtin_amdgcn_mfma_f32_16x16x32_f16(
                    a_h[mt], b_h[nt], acc[mt][nt], 0, 0, 0);
                acc[mt][nt] = __builtin_amdgcn_mfma_f32_16x16x32_f16(
                    a_h[mt], b_l[nt], acc[mt][nt], 0, 0, 0);
                acc[mt][nt] = __builtin_amdgcn_mfma_f32_16x16x32_f16(
                    a_l[mt], b_h[nt], acc[mt][nt], 0, 0, 0);
            }
        __builtin_amdgcn_s_setprio(0);
        __builtin_amdgcn_s_barrier();    // all waves consumed buf b3

        if (kt + 3 < NK) stage(kt + 3, b3);   // overwrite freed buffer

        __builtin_amdgcn_s_setprio(1);
        #pragma unroll
        for (int mt = 0; mt < 4; mt++)
            #pragma unroll
            for (int nt = 2; nt < 4; nt++) {
                acc[mt][nt] = __builtin_amdgcn_mfma_f32_16x16x32_f16(
                    a_h[mt], b_h[nt], acc[mt][nt], 0, 0, 0);
                acc[mt][nt] = __builtin_amdgcn_mfma_f32_16x16x32_f16(
                    a_h[mt], b_l[nt], acc[mt][nt], 0, 0, 0);
                acc[mt][nt] = __builtin_amdgcn_mfma_f32_16x16x32_f16(
                    a_l[mt], b_h[nt], acc[mt][nt], 0, 0, 0);
            }
        __builtin_amdgcn_s_setprio(0);

        // retire ONLY stage(kt+1); kt+2 / kt+3 stay in flight across barrier
        if (kt + 3 < NK)
            asm volatile("s_waitcnt vmcnt(12)" ::: "memory");
        else if (kt + 3 == NK)
            asm volatile("s_waitcnt vmcnt(6)" ::: "memory");
        else if (kt + 2 == NK)
            asm volatile("s_waitcnt vmcnt(0)" ::: "memory");
        __builtin_amdgcn_sched_barrier(0);
        __builtin_amdgcn_s_barrier();
        b3 = (b3 == 2) ? 0 : b3 + 1;
    }

    const int col = lane & 15, row4 = g * 4;
    if (mode == 0) {
        #pragma unroll
        for (int mt = 0; mt < 4; mt++)
            #pragma unroll
            for (int nt = 0; nt < 4; nt++) {
                const int n = bn + wn + nt * 16 + col;
                const float bv = bias[n];
                const int m0 = bm + wm + mt * 16 + row4;
                #pragma unroll
                for (int r = 0; r < 4; r++)
                    Cout[(size_t)(m0 + r) * N + n] = acc[mt][nt][r] + bv;
            }
    } else {
        #pragma unroll
        for (int mt = 0; mt < 4; mt++)
            #pragma unroll
            for (int nt = 0; nt < 4; nt++) {
                const int n = bn + wn + nt * 16 + col;
                const int which = n >> 10;
                const int cc_ = n & 1023;
                const int hh_ = cc_ >> 6, d = cc_ & 63;
                const int m0 = bm + wm + mt * 16 + row4;
                const int b = m0 >> 11, t0 = m0 & 2047;
                const size_t bhx = (size_t)b * NH + hh_;
                const float bv = bias[n];
                if (which == 0) {        // Q: split fp16 [b,h,t,d], x0.125
                    #pragma unroll
                    for (int r = 0; r < 4; r++) {
                        const float qv = (acc[mt][nt][r] + bv) * 0.125f;
                        const _Float16 qh_ = (_Float16)qv;
                        const size_t o = (bhx * TT + t0 + r) * DD + d;
                        outQh[o] = qh_;
                        outQl[o] = (_Float16)(qv - (float)qh_);
                    }
                } else if (which == 1) { // K: split fp16 [b,h,t,d]
                    #pragma unroll
                    for (int r = 0; r < 4; r++) {
                        const float kv = acc[mt][nt][r] + bv;
                        const _Float16 kh_ = (_Float16)kv;
                        const size_t o = (bhx * TT + t0 + r) * DD + d;
                        outKh[o] = kh_;
                        outKl[o] = (_Float16)(kv - (float)kh_);
                    }
                } else {                 // V: fp16 [b,h,d,t]
                    half4 vv;
                    #pragma unroll
                    for (int r = 0; r < 4; r++)
                        vv[r] = (_Float16)(acc[mt][nt][r] + bv);
                    *(half4*)&outVt[(bhx * DD + d) * TT + t0] = vv;
                }
            }
    }
}

// ---------------------------------------------------------------------------
// Sparsemax over D=64, one wave per row t, in-place on split K [b,h,t,d].
// ---------------------------------------------------------------------------
__global__ __launch_bounds__(256) void sparsemax_kernel(
    _Float16* __restrict__ Kh, _Float16* __restrict__ Kl)
{
    const int lane = threadIdx.x & 63;
    const size_t row = (size_t)blockIdx.x * 4 + (threadIdx.x >> 6);
    const size_t off = row * DD + lane;
    float z = (float)Kh[off] + (float)Kl[off];
    float cnt = 0.f, ss = 0.f;
    #pragma unroll
    for (int j = 0; j < 64; j++) {
        float zj = __shfl(z, j, 64);
        if (zj >= z) { cnt += 1.f; ss += zj; }
    }
    float cond = (1.f + cnt * z > ss) ? 1.f : 0.f;
    float rho = cond, S = cond * z;
    #pragma unroll
    for (int o = 32; o; o >>= 1) {
        rho += __shfl_xor(rho, o, 64);
        S   += __shfl_xor(S,   o, 64);
    }
    float tau = (S - 1.f) / rho;
    float outv = fmaxf(z - tau, 0.f);
    _Float16 hh = (_Float16)outv;
    Kh[off] = hh;
    Kl[off] = (_Float16)(outv - (float)hh);
}

// ---------------------------------------------------------------------------
// MFMA flash attention + XSA correction (unchanged from passing round 3).
// ---------------------------------------------------------------------------
__global__ __launch_bounds__(256, 2) void attn_kernel(
    const _Float16* __restrict__ Qh, const _Float16* __restrict__ Ql,
    const _Float16* __restrict__ Kh, const _Float16* __restrict__ Kl,
    const _Float16* __restrict__ Vt,
    _Float16* __restrict__ Yh, _Float16* __restrict__ Yl)
{
    __shared__ _Float16 sKh[2][64 * DD];
    __shared__ _Float16 sKl[2][64 * DD];
    __shared__ _Float16 sV [2][64 * DD];   // [d][kv], swizzled — 48 KB total

    const int tid = threadIdx.x;
    const int w = tid >> 6, lane = tid & 63;
    const int p = blockIdx.x >> 6;       // tile pair
    const int bhid = blockIdx.x & 63;    // blk%8 == bhid%8 -> head-per-XCD
    const int b = bhid >> 4, h = bhid & 15;
    const size_t bh = (size_t)b * NH + h;
    const _Float16* Qhg = Qh + bh * (size_t)TT * DD;
    const _Float16* Qlg = Ql + bh * (size_t)TT * DD;
    const _Float16* Khg = Kh + bh * (size_t)TT * DD;
    const _Float16* Klg = Kl + bh * (size_t)TT * DD;
    const _Float16* Vtg = Vt + bh * (size_t)DD * TT;

    const int qrow = lane & 15;
    const int g = lane >> 4;
    const int swz = qrow & 7;
    const int sr = lane >> 3;            // staging row-in-chunk 0..7
    const int uu = (lane & 7) ^ sr;      // pre-swizzled source 16B-unit

    auto stage = [&](int kt, int buf) {
        const int rb = w * 16;
        #pragma unroll
        for (int i = 0; i < 2; i++) {
            const int rr = rb + i * 8 + sr;
            const size_t ko = (size_t)(kt * 64 + rr) * DD + (uu << 3);
            gload16(&Khg[ko], &sKh[buf][(rb + i * 8) * DD]);
            gload16(&Klg[ko], &sKl[buf][(rb + i * 8) * DD]);
            gload16(&Vtg[(size_t)rr * TT + kt * 64 + (uu << 3)],
                    &sV[buf][(rb + i * 8) * DD]);
        }
    };

    const int qlist[2] = {p, 15 - p};
    int cur = 0;

    for (int qi = 0; qi < 2; qi++) {
        const int qt = qlist[qi];
        const int wq0 = qt * 128 + w * 32;
        const int wqmax = wq0 + 31;
        const int nkv = 2 * qt + 2;

        // Q fragments (B-operand of swapped S^T MFMA), hi+lo
        half8 qfh[2][2], qfl[2][2];
        #pragma unroll
        for (int nq = 0; nq < 2; nq++)
            #pragma unroll
            for (int ks = 0; ks < 2; ks++) {
                const size_t o = (size_t)(wq0 + nq * 16 + qrow) * DD
                               + (g << 3) + (ks << 5);
                qfh[nq][ks] = *(const half8*)&Qhg[o];
                qfl[nq][ks] = *(const half8*)&Qlg[o];
            }

        floatx4 acc[2][4];
        #pragma unroll
        for (int i = 0; i < 2; i++)
            #pragma unroll
            for (int j = 0; j < 4; j++)
                acc[i][j] = (floatx4){0.f, 0.f, 0.f, 0.f};
        float m_i[2] = {-3.0e38f, -3.0e38f};
        float l_i[2] = {0.f, 0.f};

        __syncthreads();
        stage(0, cur);

        for (int kt = 0; kt < nkv; kt++) {
            __syncthreads();               // drains vmcnt: buf[cur] ready
            if (kt + 1 < nkv) stage(kt + 1, cur ^ 1);

            if (kt * 64 <= wqmax) {        // wave not fully masked
                const _Float16* kb = sKh[cur];
                const _Float16* lb = sKl[cur];
                const _Float16* vbp = sV[cur];

                // S^T = K x Q^T (3-term split): D[kv][q]
                floatx4 s[4][2];
                #pragma unroll
                for (int mk = 0; mk < 4; mk++)
                    #pragma unroll
                    for (int nq = 0; nq < 2; nq++)
                        s[mk][nq] = (floatx4){0.f, 0.f, 0.f, 0.f};

                #pragma unroll
                for (int mk = 0; mk < 4; mk++) {
                    #pragma unroll
                    for (int ks = 0; ks < 2; ks++) {
                        const int off = (qrow + mk * 16) * DD
                                      + (((g + (ks << 2)) ^ swz) << 3);
                        const half8 kfh = *(const half8*)&kb[off];
                        const half8 kfl = *(const half8*)&lb[off];
                        #pragma unroll
                        for (int nq = 0; nq < 2; nq++) {
                            s[mk][nq] = __builtin_amdgcn_mfma_f32_16x16x32_f16(
                                kfh, qfh[nq][ks], s[mk][nq], 0, 0, 0);
                            s[mk][nq] = __builtin_amdgcn_mfma_f32_16x16x32_f16(
                                kfh, qfl[nq][ks], s[mk][nq], 0, 0, 0);
                            s[mk][nq] = __builtin_amdgcn_mfma_f32_16x16x32_f16(
                                kfl, qfh[nq][ks], s[mk][nq], 0, 0, 0);
                        }
                    }
                }

                // causal mask (diagonal tiles only)
                if (kt * 64 + 63 > wq0) {
                    #pragma unroll
                    for (int mk = 0; mk < 4; mk++)
                        #pragma unroll
                        for (int nq = 0; nq < 2; nq++)
                            #pragma unroll
                            for (int r = 0; r < 4; r++) {
                                const int kvg = kt * 64 + mk * 16 + (g << 2) + r;
                                const int qg  = wq0 + nq * 16 + qrow;
                                if (kvg > qg) s[mk][nq][r] = -1.0e30f;
                            }
                }

                // online softmax: per lane 16 kv-vals per q-col, 2 shfl hops
                float al_[2];
                #pragma unroll
                for (int nq = 0; nq < 2; nq++) {
                    float mx = s[0][nq][0];
                    #pragma unroll
                    for (int mk = 0; mk < 4; mk++)
                        #pragma unroll
                        for (int r = 0; r < 4; r++)
                            mx = fmaxf(mx, s[mk][nq][r]);
                    mx = fmaxf(mx, __shfl_xor(mx, 16, 64));
                    mx = fmaxf(mx, __shfl_xor(mx, 32, 64));
                    const float mn = fmaxf(m_i[nq], mx);
                    al_[nq] = __expf(m_i[nq] - mn);
                    m_i[nq] = mn;
                    float r0 = 0.f;
                    #pragma unroll
                    for (int mk = 0; mk < 4; mk++)
                        #pragma unroll
                        for (int r = 0; r < 4; r++) {
                            const float pp = __expf(s[mk][nq][r] - mn);
                            s[mk][nq][r] = pp;
                            r0 += pp;
                        }
                    r0 += __shfl_xor(r0, 16, 64);
                    r0 += __shfl_xor(r0, 32, 64);
                    l_i[nq] = l_i[nq] * al_[nq] + r0;
                }

                // rescale acc (alpha broadcast: stats live at lane = q&15)
                #pragma unroll
                for (int mt = 0; mt < 2; mt++)
                    #pragma unroll
                    for (int r = 0; r < 4; r++) {
                        const float aB = __shfl(al_[mt], (g << 2) | r, 64);
                        #pragma unroll
                        for (int nt = 0; nt < 4; nt++)
                            acc[mt][nt][r] *= aB;
                    }

                // P -> split fp16 in registers (already in PV A-frag layout)
                half4 ph[4][2], pl[4][2];
                #pragma unroll
                for (int mk = 0; mk < 4; mk++)
                    #pragma unroll
                    for (int nq = 0; nq < 2; nq++)
                        #pragma unroll
                        for (int r = 0; r < 4; r++) {
                            const float pv = s[mk][nq][r];
                            const _Float16 hh = (_Float16)pv;
                            ph[mk][nq][r] = hh;
                            pl[mk][nq][r] = (_Float16)(pv - (float)hh);
                        }

                // PV: acc[q][d] += P x V  (16x16x16, 2-term P split)
                #pragma unroll
                for (int mk = 0; mk < 4; mk++) {
                    #pragma unroll
                    for (int nt = 0; nt < 4; nt++) {
                        const int d = qrow + nt * 16;
                        const int u = ((mk << 1) | (g >> 1)) ^ swz;
                        const half4 vb = *(const half4*)
                            &vbp[d * DD + (u << 3) + ((g & 1) << 2)];
                        #pragma unroll
                        for (int nq = 0; nq < 2; nq++) {
                            acc[nq][nt] = __builtin_amdgcn_mfma_f32_16x16x16f16(
                                ph[mk][nq], vb, acc[nq][nt], 0, 0, 0);
                            acc[nq][nt] = __builtin_amdgcn_mfma_f32_16x16x16f16(
                                pl[mk][nq], vb, acc[nq][nt], 0, 0, 0);
                        }
                    }
                }
            }
            cur ^= 1;
        }

        // epilogue: normalize, XSA correction, split store
        #pragma unroll
        for (int mt = 0; mt < 2; mt++)
            #pragma unroll
            for (int r = 0; r < 4; r++) {
                const int qg = wq0 + mt * 16 + (g << 2) + r;
                const float invl = 1.0f / __shfl(l_i[mt], (g << 2) | r, 64);
                float y0 = acc[mt][0][r] * invl;
                float y1 = acc[mt][1][r] * invl;
                float y2 = acc[mt][2][r] * invl;
                float y3 = acc[mt][3][r] * invl;
                const float v0 = (float)Vtg[(size_t)qrow * TT + qg];
                const float v1 = (float)Vtg[(size_t)(qrow + 16) * TT + qg];
                const float v2 = (float)Vtg[(size_t)(qrow + 32) * TT + qg];
                const float v3 = (float)Vtg[(size_t)(qrow + 48) * TT + qg];
                float n2 = v0 * v0 + v1 * v1 + v2 * v2 + v3 * v3;
                #pragma unroll
                for (int o = 8; o; o >>= 1) n2 += __shfl_xor(n2, o, 64);
                const float ivn = 1.0f / fmaxf(sqrtf(n2), 1e-12f);
                float coef = y0 * v0 + y1 * v1 + y2 * v2 + y3 * v3;
                #pragma unroll
                for (int o = 8; o; o >>= 1) coef += __shfl_xor(coef, o, 64);
                coef *= ivn * ivn;
                const float o0 = y0 - coef * v0;
                const float o1 = y1 - coef * v1;
                const float o2 = y2 - coef * v2;
                const float o3 = y3 - coef * v3;
                const size_t ob = ((size_t)(b * TT + qg)) * CC + h * DD + qrow;
                _Float16 hh;
                hh = (_Float16)o0; Yh[ob]      = hh; Yl[ob]      = (_Float16)(o0 - (float)hh);
                hh = (_Float16)o1; Yh[ob + 16] = hh; Yl[ob + 16] = (_Float16)(o1 - (float)hh);
                hh = (_Float16)o2; Yh[ob + 32] = hh; Yl[ob + 32] = (_Float16)(o2 - (float)hh);
                hh = (_Float16)o3; Yh[ob + 48] = hh; Yl[ob + 48] = (_Float16)(o3 - (float)hh);
            }
    }
}

// ---------------------------------------------------------------------------
extern "C" void kernel_launch(void* const* d_in, const int* in_sizes, int n_in,
                              void* d_out, int out_size, void* d_ws, size_t ws_size,
                              hipStream_t stream) {
    const float* x      = (const float*)d_in[0];
    const float* W_attn = (const float*)d_in[1];
    const float* b_attn = (const float*)d_in[2];
    const float* W_proj = (const float*)d_in[3];
    const float* b_proj = (const float*)d_in[4];
    float* out = (float*)d_out;

    // workspace layout (124 MiB):
    // [0,16)    xh fp16 (dead after gemm1; reused as Yh)
    // [16,32)   xl fp16 (dead after gemm1; reused as Yl)
    // [32,38)   WhT fp16 ([32,34) reused for W_proj hi)
    // [38,44)   WlT fp16 ([34,36) reused for W_proj lo)
    // [44,60)   Qh fp16 [b,h,t,d] scaled
    // [60,76)   Ql fp16 [b,h,t,d] scaled
    // [76,92)   Kh fp16 [b,h,t,d]
    // [92,108)  Kl fp16 [b,h,t,d]
    // [108,124) Vt fp16 [b,h,d,t]
    char* ws = (char*)d_ws;
    _Float16* xh   = (_Float16*)(ws);
    _Float16* xl   = (_Float16*)(ws + ((size_t)16 << 20));
    _Float16* WhT  = (_Float16*)(ws + ((size_t)32 << 20));
    _Float16* WlT  = (_Float16*)(ws + ((size_t)38 << 20));
    _Float16* Qh_  = (_Float16*)(ws + ((size_t)44 << 20));
    _Float16* Ql_  = (_Float16*)(ws + ((size_t)60 << 20));
    _Float16* Kh_  = (_Float16*)(ws + ((size_t)76 << 20));
    _Float16* Kl_  = (_Float16*)(ws + ((size_t)92 << 20));
    _Float16* Vt_  = (_Float16*)(ws + ((size_t)108 << 20));
    _Float16* Yh   = xh;
    _Float16* Yl   = xl;
    _Float16* WphT = WhT;
    _Float16* WplT = (_Float16*)(ws + ((size_t)34 << 20));

    split_x_kernel<<<(MM * CC) / (256 * 4), 256, 0, stream>>>(x, xh, xl);
    splitT_w_kernel<<<dim3(3 * CC / 64, CC / 64), 256, 0, stream>>>(
        W_attn, WhT, WlT, CC, 3 * CC);
    // QKV GEMM: grid 64 x 12 = 768 blocks
    gemm_ht3_kernel<<<dim3((MM / 128) * (3 * CC / 256)), 512, 0, stream>>>(
        xh, xl, WhT, WlT, b_attn, nullptr,
        Qh_, Ql_, Kh_, Kl_, Vt_, 3 * CC, CC, 3 * CC / 256, 1);
    sparsemax_kernel<<<dim3((NB * NH * TT) / 4), 256, 0, stream>>>(Kh_, Kl_);
    attn_kernel<<<dim3(512), 256, 0, stream>>>(Qh_, Ql_, Kh_, Kl_, Vt_, Yh, Yl);
    splitT_w_kernel<<<dim3(CC / 64, CC / 64), 256, 0, stream>>>(
        W_proj, WphT, WplT, CC, CC);
    // proj GEMM: grid 64 x 4 = 256 blocks
    gemm_ht3_kernel<<<dim3((MM / 128) * (CC / 256)), 512, 0, stream>>>(
        Yh, Yl, WphT, WplT, b_proj, out,
        nullptr, nullptr, nullptr, nullptr, nullptr, CC, CC, CC / 256, 0);
}

// Round 10
// 491.893 us; speedup vs baseline: 1.8710x; 1.0715x over previous
//
#include <hip/hip_runtime.h>
#include <math.h>

#define NB 4
#define NH 16
#define TT 2048
#define CC 1024
#define DD 64
#define MM (NB * TT)   // 8192
#define BK 32

typedef __attribute__((ext_vector_type(8))) _Float16 half8;
typedef __attribute__((ext_vector_type(4))) _Float16 half4;
typedef __attribute__((ext_vector_type(4))) float floatx4;

// ---------------------------------------------------------------------------
// async global->LDS, 16B per lane (linear dest = wave-uniform base + lane*16)
// ---------------------------------------------------------------------------
__device__ __forceinline__ void gload16(const _Float16* g, _Float16* l) {
    auto gp = (const __attribute__((address_space(1))) void*)(uintptr_t)g;
    auto lp = (__attribute__((address_space(3))) void*)(uint32_t)(uintptr_t)l;
    __builtin_amdgcn_global_load_lds(gp, lp, 16, 0, 0);
}

// ---------------------------------------------------------------------------
// Elementwise split: x fp32 -> xh + xl (fp16 pair), same [M,K] layout.
// ---------------------------------------------------------------------------
__global__ __launch_bounds__(256) void split_x_kernel(
    const float* __restrict__ x, _Float16* __restrict__ xh,
    _Float16* __restrict__ xl)
{
    size_t i = ((size_t)blockIdx.x * 256 + threadIdx.x) * 4;
    float4 v = *(const float4*)&x[i];
    half4 h, l;
    h.x = (_Float16)v.x; l.x = (_Float16)(v.x - (float)h.x);
    h.y = (_Float16)v.y; l.y = (_Float16)(v.y - (float)h.y);
    h.z = (_Float16)v.z; l.z = (_Float16)(v.z - (float)h.z);
    h.w = (_Float16)v.w; l.w = (_Float16)(v.w - (float)h.w);
    *(half4*)&xh[i] = h;
    *(half4*)&xl[i] = l;
}

// ---------------------------------------------------------------------------
// Transpose + split: W [K,N] fp32 -> WhT + WlT [N,K] fp16 (k-major for MFMA).
// ---------------------------------------------------------------------------
__global__ __launch_bounds__(256) void splitT_w_kernel(
    const float* __restrict__ W, _Float16* __restrict__ WhT,
    _Float16* __restrict__ WlT, int K, int N)
{
    __shared__ float Ls[64][65];
    const int bN = blockIdx.x * 64;
    const int bK = blockIdx.y * 64;
    const int tid = threadIdx.x;
    const int g = tid >> 4, c = tid & 15;

    #pragma unroll
    for (int u = 0; u < 4; u++) {
        int r = u * 16 + g;
        float4 v = *(const float4*)&W[(size_t)(bK + r) * N + bN + c * 4];
        Ls[r][c * 4 + 0] = v.x; Ls[r][c * 4 + 1] = v.y;
        Ls[r][c * 4 + 2] = v.z; Ls[r][c * 4 + 3] = v.w;
    }
    __syncthreads();
    #pragma unroll
    for (int u = 0; u < 4; u++) {
        int n = u * 16 + g;
        half4 h, l;
        float f;
        f = Ls[c * 4 + 0][n]; h.x = (_Float16)f; l.x = (_Float16)(f - (float)h.x);
        f = Ls[c * 4 + 1][n]; h.y = (_Float16)f; l.y = (_Float16)(f - (float)h.y);
        f = Ls[c * 4 + 2][n]; h.z = (_Float16)f; l.z = (_Float16)(f - (float)h.z);
        f = Ls[c * 4 + 3][n]; h.w = (_Float16)f; l.w = (_Float16)(f - (float)h.w);
        size_t o = (size_t)(bN + n) * K + bK + c * 4;
        *(half4*)&WhT[o] = h;
        *(half4*)&WlT[o] = l;
    }
}

// ---------------------------------------------------------------------------
// Split-fp16 MFMA GEMM (round-3 verified structure, 154 us QKV):
// C[M,N] = (Ah+Al)[M,K] x (Bh+Bl)^T[N,K] + bias, 3-term split.
// BM=128, BN=256, BK=32; 512 thr = 8 waves (2M x 4N), 64x64 per wave.
// global_load_lds staging, unit-XOR swizzle, double-buffered, 96 KB LDS.
// mode 0: Cout fp32 + bias
// mode 1: qkv scatter: Q -> fp16 split [b,h,t,d] x0.125; K -> fp16 split
//         [b,h,t,d]; V -> fp16 [b,h,d,t]
// ---------------------------------------------------------------------------
__global__ __launch_bounds__(512, 2) void gemm_ht3_kernel(
    const _Float16* __restrict__ Ah, const _Float16* __restrict__ Al,
    const _Float16* __restrict__ Bh, const _Float16* __restrict__ Bl,
    const float* __restrict__ bias, float* __restrict__ Cout,
    _Float16* __restrict__ outQh, _Float16* __restrict__ outQl,
    _Float16* __restrict__ outKh, _Float16* __restrict__ outKl,
    _Float16* __restrict__ outVt, int N, int K, int nbx, int mode)
{
    __shared__ _Float16 sAh[2][128 * BK], sAl[2][128 * BK];
    __shared__ _Float16 sBh[2][256 * BK], sBl[2][256 * BK];   // 96 KB

    // XCD-chunked block swizzle (nblk % 8 == 0 for both launches)
    const int nblk = gridDim.x;
    const int id = blockIdx.x;
    const int swzid = (id & 7) * (nblk >> 3) + (id >> 3);
    const int by = swzid / nbx, bx = swzid - by * nbx;
    const int bm = by * 128, bn = bx * 256;

    const int tid = threadIdx.x;
    const int w = tid >> 6, lane = tid & 63;
    const int wm = (w >> 2) * 64, wn = (w & 3) * 64;
    const int fr = lane & 15, g = lane >> 4;

    const int rS = w * 16 + (lane >> 2);
    const int ug = ((lane & 3) ^ ((rS >> 1) & 3)) * 8;   // halfs
    const size_t gA  = (size_t)(bm + rS) * K + ug;
    const size_t gB0 = (size_t)(bn + rS) * K + ug;
    const size_t gB1 = (size_t)(bn + 128 + rS) * K + ug;
    const int ldsW = w * 16 * BK;

    auto stage = [&](int kt, int c) {
        const int k0 = kt * BK;
        gload16(&Ah[gA + k0],  &sAh[c][ldsW]);
        gload16(&Al[gA + k0],  &sAl[c][ldsW]);
        gload16(&Bh[gB0 + k0], &sBh[c][ldsW]);
        gload16(&Bl[gB0 + k0], &sBl[c][ldsW]);
        gload16(&Bh[gB1 + k0], &sBh[c][128 * BK + ldsW]);
        gload16(&Bl[gB1 + k0], &sBl[c][128 * BK + ldsW]);
    };

    int offA[4], offB[4];
    #pragma unroll
    for (int t = 0; t < 4; t++) {
        const int ra = wm + t * 16 + fr;
        offA[t] = ra * BK + ((g ^ ((ra >> 1) & 3)) << 3);
        const int rb = wn + t * 16 + fr;
        offB[t] = rb * BK + ((g ^ ((rb >> 1) & 3)) << 3);
    }

    floatx4 acc[4][4];
    #pragma unroll
    for (int i = 0; i < 4; i++)
        #pragma unroll
        for (int j = 0; j < 4; j++)
            acc[i][j] = (floatx4){0.f, 0.f, 0.f, 0.f};

    stage(0, 0);
    stage(1, 1);
    __syncthreads();

    const int NK = K >> 5;
    for (int kt = 0; kt < NK; kt++) {
        const int c = kt & 1;
        half8 a_h[4], a_l[4], b_h[4], b_l[4];
        #pragma unroll
        for (int t = 0; t < 4; t++) {
            a_h[t] = *(const half8*)&sAh[c][offA[t]];
            a_l[t] = *(const half8*)&sAl[c][offA[t]];
            b_h[t] = *(const half8*)&sBh[c][offB[t]];
            b_l[t] = *(const half8*)&sBl[c][offB[t]];
        }
        __builtin_amdgcn_s_setprio(1);
        #pragma unroll
        for (int mt = 0; mt < 4; mt++)
            #pragma unroll
            for (int nt = 0; nt < 4; nt++) {
                acc[mt][nt] = __builtin_amdgcn_mfma_f32_16x16x32_f16(
                    a_h[mt], b_h[nt], acc[mt][nt], 0, 0, 0);
                acc[mt][nt] = __builtin_amdgcn_mfma_f32_16x16x32_f16(
                    a_h[mt], b_l[nt], acc[mt][nt], 0, 0, 0);
                acc[mt][nt] = __builtin_amdgcn_mfma_f32_16x16x32_f16(
                    a_l[mt], b_h[nt], acc[mt][nt], 0, 0, 0);
            }
        __builtin_amdgcn_s_setprio(0);
        __syncthreads();
        if (kt + 2 < NK) stage(kt + 2, c);
    }

    const int col = lane & 15, row4 = g * 4;
    if (mode == 0) {
        #pragma unroll
        for (int mt = 0; mt < 4; mt++)
            #pragma unroll
            for (int nt = 0; nt < 4; nt++) {
                const int n = bn + wn + nt * 16 + col;
                const float bv = bias[n];
                const int m0 = bm + wm + mt * 16 + row4;
                #pragma unroll
                for (int r = 0; r < 4; r++)
                    Cout[(size_t)(m0 + r) * N + n] = acc[mt][nt][r] + bv;
            }
    } else {
        #pragma unroll
        for (int mt = 0; mt < 4; mt++)
            #pragma unroll
            for (int nt = 0; nt < 4; nt++) {
                const int n = bn + wn + nt * 16 + col;
                const int which = n >> 10;
                const int cc_ = n & 1023;
                const int hh_ = cc_ >> 6, d = cc_ & 63;
                const int m0 = bm + wm + mt * 16 + row4;
                const int b = m0 >> 11, t0 = m0 & 2047;
                const size_t bhx = (size_t)b * NH + hh_;
                const float bv = bias[n];
                if (which == 0) {        // Q: split fp16 [b,h,t,d], x0.125
                    #pragma unroll
                    for (int r = 0; r < 4; r++) {
                        const float qv = (acc[mt][nt][r] + bv) * 0.125f;
                        const _Float16 qh_ = (_Float16)qv;
                        const size_t o = (bhx * TT + t0 + r) * DD + d;
                        outQh[o] = qh_;
                        outQl[o] = (_Float16)(qv - (float)qh_);
                    }
                } else if (which == 1) { // K: split fp16 [b,h,t,d]
                    #pragma unroll
                    for (int r = 0; r < 4; r++) {
                        const float kv = acc[mt][nt][r] + bv;
                        const _Float16 kh_ = (_Float16)kv;
                        const size_t o = (bhx * TT + t0 + r) * DD + d;
                        outKh[o] = kh_;
                        outKl[o] = (_Float16)(kv - (float)kh_);
                    }
                } else {                 // V: fp16 [b,h,d,t]
                    half4 vv;
                    #pragma unroll
                    for (int r = 0; r < 4; r++)
                        vv[r] = (_Float16)(acc[mt][nt][r] + bv);
                    *(half4*)&outVt[(bhx * DD + d) * TT + t0] = vv;
                }
            }
    }
}

// ---------------------------------------------------------------------------
// Sparsemax over D=64, one wave per row t. Reads split K (hi+lo ~fp32
// precision, protecting the pre-sparsemax GEMM accuracy); writes the
// sparsemax output as SINGLE fp16 into Kh. Output k in [0,1] with
// sum_d k = 1, so fp16 rounding of the OUTPUT contributes only ~2^-11
// to downstream logits (negligible); Kl is left unused by attn.
// ---------------------------------------------------------------------------
__global__ __launch_bounds__(256) void sparsemax_kernel(
    _Float16* __restrict__ Kh, const _Float16* __restrict__ Kl)
{
    const int lane = threadIdx.x & 63;
    const size_t row = (size_t)blockIdx.x * 4 + (threadIdx.x >> 6);
    const size_t off = row * DD + lane;
    float z = (float)Kh[off] + (float)Kl[off];
    float cnt = 0.f, ss = 0.f;
    #pragma unroll
    for (int j = 0; j < 64; j++) {
        float zj = __shfl(z, j, 64);
        if (zj >= z) { cnt += 1.f; ss += zj; }
    }
    float cond = (1.f + cnt * z > ss) ? 1.f : 0.f;
    float rho = cond, S = cond * z;
    #pragma unroll
    for (int o = 32; o; o >>= 1) {
        rho += __shfl_xor(rho, o, 64);
        S   += __shfl_xor(S,   o, 64);
    }
    float tau = (S - 1.f) / rho;
    Kh[off] = (_Float16)fmaxf(z - tau, 0.f);
}

// ---------------------------------------------------------------------------
// MFMA flash attention + XSA correction. Structure = round-2/3 verified
// kernel, with the numerically-negligible lo paths DELETED (deletions only):
// post-sparsemax k is bounded (sum=1), so QK lo-terms are O(2^-11) in
// logits -> QK single-term (16 MFMA/tile). P in [0,1] sum=1 -> PV
// single-term (32 MFMA/tile). Q read hi-only; K single (sparsemax out);
// epilogue still writes split Yh/Yl for the split proj GEMM.
// LDS 32 KB (sK + sV double-buffered).
// ---------------------------------------------------------------------------
__global__ __launch_bounds__(256, 2) void attn_kernel(
    const _Float16* __restrict__ Qh, const _Float16* __restrict__ Kh,
    const _Float16* __restrict__ Vt,
    _Float16* __restrict__ Yh, _Float16* __restrict__ Yl)
{
    __shared__ _Float16 sK[2][64 * DD];
    __shared__ _Float16 sV[2][64 * DD];   // 32 KB total

    const int tid = threadIdx.x;
    const int w = tid >> 6, lane = tid & 63;
    const int p = blockIdx.x >> 6;       // tile pair
    const int bhid = blockIdx.x & 63;    // blk%8 == bhid%8 -> head-per-XCD
    const int b = bhid >> 4, h = bhid & 15;
    const size_t bh = (size_t)b * NH + h;
    const _Float16* Qhg = Qh + bh * (size_t)TT * DD;
    const _Float16* Khg = Kh + bh * (size_t)TT * DD;
    const _Float16* Vtg = Vt + bh * (size_t)DD * TT;

    const int qrow = lane & 15;
    const int g = lane >> 4;
    const int swz = qrow & 7;
    const int sr = lane >> 3;            // staging row-in-chunk 0..7
    const int uu = (lane & 7) ^ sr;      // pre-swizzled source 16B-unit

    auto stage = [&](int kt, int buf) {
        const int rb = w * 16;
        #pragma unroll
        for (int i = 0; i < 2; i++) {
            const int rr = rb + i * 8 + sr;
            gload16(&Khg[(size_t)(kt * 64 + rr) * DD + (uu << 3)],
                    &sK[buf][(rb + i * 8) * DD]);
            gload16(&Vtg[(size_t)rr * TT + kt * 64 + (uu << 3)],
                    &sV[buf][(rb + i * 8) * DD]);
        }
    };

    const int qlist[2] = {p, 15 - p};
    int cur = 0;

    for (int qi = 0; qi < 2; qi++) {
        const int qt = qlist[qi];
        const int wq0 = qt * 128 + w * 32;
        const int wqmax = wq0 + 31;
        const int nkv = 2 * qt + 2;

        // Q fragments (B-operand of swapped S^T MFMA), hi only
        half8 qf[2][2];
        #pragma unroll
        for (int nq = 0; nq < 2; nq++)
            #pragma unroll
            for (int ks = 0; ks < 2; ks++)
                qf[nq][ks] = *(const half8*)&Qhg[
                    (size_t)(wq0 + nq * 16 + qrow) * DD + (g << 3) + (ks << 5)];

        floatx4 acc[2][4];
        #pragma unroll
        for (int i = 0; i < 2; i++)
            #pragma unroll
            for (int j = 0; j < 4; j++)
                acc[i][j] = (floatx4){0.f, 0.f, 0.f, 0.f};
        float m_i[2] = {-3.0e38f, -3.0e38f};
        float l_i[2] = {0.f, 0.f};

        __syncthreads();
        stage(0, cur);

        for (int kt = 0; kt < nkv; kt++) {
            __syncthreads();               // drains vmcnt: buf[cur] ready
            if (kt + 1 < nkv) stage(kt + 1, cur ^ 1);

            if (kt * 64 <= wqmax) {        // wave not fully masked
                const _Float16* kb = sK[cur];
                const _Float16* vbp = sV[cur];

                // S^T = K x Q^T: D[kv][q]
                floatx4 s[4][2];
                #pragma unroll
                for (int mk = 0; mk < 4; mk++)
                    #pragma unroll
                    for (int nq = 0; nq < 2; nq++)
                        s[mk][nq] = (floatx4){0.f, 0.f, 0.f, 0.f};

                #pragma unroll
                for (int mk = 0; mk < 4; mk++) {
                    #pragma unroll
                    for (int ks = 0; ks < 2; ks++) {
                        const half8 kf = *(const half8*)&kb[
                            (qrow + mk * 16) * DD + (((g + (ks << 2)) ^ swz) << 3)];
                        #pragma unroll
                        for (int nq = 0; nq < 2; nq++)
                            s[mk][nq] = __builtin_amdgcn_mfma_f32_16x16x32_f16(
                                kf, qf[nq][ks], s[mk][nq], 0, 0, 0);
                    }
                }

                // causal mask (diagonal tiles only)
                if (kt * 64 + 63 > wq0) {
                    #pragma unroll
                    for (int mk = 0; mk < 4; mk++)
                        #pragma unroll
                        for (int nq = 0; nq < 2; nq++)
                            #pragma unroll
                            for (int r = 0; r < 4; r++) {
                                const int kvg = kt * 64 + mk * 16 + (g << 2) + r;
                                const int qg  = wq0 + nq * 16 + qrow;
                                if (kvg > qg) s[mk][nq][r] = -1.0e30f;
                            }
                }

                // online softmax: per lane 16 kv-vals per q-col, 2 shfl hops
                float al_[2];
                #pragma unroll
                for (int nq = 0; nq < 2; nq++) {
                    float mx = s[0][nq][0];
                    #pragma unroll
                    for (int mk = 0; mk < 4; mk++)
                        #pragma unroll
                        for (int r = 0; r < 4; r++)
                            mx = fmaxf(mx, s[mk][nq][r]);
                    mx = fmaxf(mx, __shfl_xor(mx, 16, 64));
                    mx = fmaxf(mx, __shfl_xor(mx, 32, 64));
                    const float mn = fmaxf(m_i[nq], mx);
                    al_[nq] = __expf(m_i[nq] - mn);
                    m_i[nq] = mn;
                    float r0 = 0.f;
                    #pragma unroll
                    for (int mk = 0; mk < 4; mk++)
                        #pragma unroll
                        for (int r = 0; r < 4; r++) {
                            const float pp = __expf(s[mk][nq][r] - mn);
                            s[mk][nq][r] = pp;
                            r0 += pp;
                        }
                    r0 += __shfl_xor(r0, 16, 64);
                    r0 += __shfl_xor(r0, 32, 64);
                    l_i[nq] = l_i[nq] * al_[nq] + r0;
                }

                // rescale acc (alpha broadcast: stats live at lane = q&15)
                #pragma unroll
                for (int mt = 0; mt < 2; mt++)
                    #pragma unroll
                    for (int r = 0; r < 4; r++) {
                        const float aB = __shfl(al_[mt], (g << 2) | r, 64);
                        #pragma unroll
                        for (int nt = 0; nt < 4; nt++)
                            acc[mt][nt][r] *= aB;
                    }

                // P -> fp16 in registers (already in PV A-frag layout)
                half4 ph[4][2];
                #pragma unroll
                for (int mk = 0; mk < 4; mk++)
                    #pragma unroll
                    for (int nq = 0; nq < 2; nq++)
                        #pragma unroll
                        for (int r = 0; r < 4; r++)
                            ph[mk][nq][r] = (_Float16)s[mk][nq][r];

                // PV: acc[q][d] += P x V  (16x16x16, single-term)
                #pragma unroll
                for (int mk = 0; mk < 4; mk++) {
                    #pragma unroll
                    for (int nt = 0; nt < 4; nt++) {
                        const int d = qrow + nt * 16;
                        const int u = ((mk << 1) | (g >> 1)) ^ swz;
                        const half4 vb = *(const half4*)
                            &vbp[d * DD + (u << 3) + ((g & 1) << 2)];
                        #pragma unroll
                        for (int nq = 0; nq < 2; nq++)
                            acc[nq][nt] = __builtin_amdgcn_mfma_f32_16x16x16f16(
                                ph[mk][nq], vb, acc[nq][nt], 0, 0, 0);
                    }
                }
            }
            cur ^= 1;
        }

        // epilogue: normalize, XSA correction, split store (proj stays split)
        #pragma unroll
        for (int mt = 0; mt < 2; mt++)
            #pragma unroll
            for (int r = 0; r < 4; r++) {
                const int qg = wq0 + mt * 16 + (g << 2) + r;
                const float invl = 1.0f / __shfl(l_i[mt], (g << 2) | r, 64);
                float y0 = acc[mt][0][r] * invl;
                float y1 = acc[mt][1][r] * invl;
                float y2 = acc[mt][2][r] * invl;
                float y3 = acc[mt][3][r] * invl;
                const float v0 = (float)Vtg[(size_t)qrow * TT + qg];
                const float v1 = (float)Vtg[(size_t)(qrow + 16) * TT + qg];
                const float v2 = (float)Vtg[(size_t)(qrow + 32) * TT + qg];
                const float v3 = (float)Vtg[(size_t)(qrow + 48) * TT + qg];
                float n2 = v0 * v0 + v1 * v1 + v2 * v2 + v3 * v3;
                #pragma unroll
                for (int o = 8; o; o >>= 1) n2 += __shfl_xor(n2, o, 64);
                const float ivn = 1.0f / fmaxf(sqrtf(n2), 1e-12f);
                float coef = y0 * v0 + y1 * v1 + y2 * v2 + y3 * v3;
                #pragma unroll
                for (int o = 8; o; o >>= 1) coef += __shfl_xor(coef, o, 64);
                coef *= ivn * ivn;
                const float o0 = y0 - coef * v0;
                const float o1 = y1 - coef * v1;
                const float o2 = y2 - coef * v2;
                const float o3 = y3 - coef * v3;
                const size_t ob = ((size_t)(b * TT + qg)) * CC + h * DD + qrow;
                _Float16 hh;
                hh = (_Float16)o0; Yh[ob]      = hh; Yl[ob]      = (_Float16)(o0 - (float)hh);
                hh = (_Float16)o1; Yh[ob + 16] = hh; Yl[ob + 16] = (_Float16)(o1 - (float)hh);
                hh = (_Float16)o2; Yh[ob + 32] = hh; Yl[ob + 32] = (_Float16)(o2 - (float)hh);
                hh = (_Float16)o3; Yh[ob + 48] = hh; Yl[ob + 48] = (_Float16)(o3 - (float)hh);
            }
    }
}

// ---------------------------------------------------------------------------
extern "C" void kernel_launch(void* const* d_in, const int* in_sizes, int n_in,
                              void* d_out, int out_size, void* d_ws, size_t ws_size,
                              hipStream_t stream) {
    const float* x      = (const float*)d_in[0];
    const float* W_attn = (const float*)d_in[1];
    const float* b_attn = (const float*)d_in[2];
    const float* W_proj = (const float*)d_in[3];
    const float* b_proj = (const float*)d_in[4];
    float* out = (float*)d_out;

    // workspace layout (124 MiB):
    // [0,16)    xh fp16 (dead after gemm1; reused as Yh)
    // [16,32)   xl fp16 (dead after gemm1; reused as Yl)
    // [32,38)   WhT fp16 ([32,34) reused for W_proj hi)
    // [38,44)   WlT fp16 ([34,36) reused for W_proj lo)
    // [44,60)   Qh fp16 [b,h,t,d] scaled
    // [60,76)   Ql fp16 [b,h,t,d] scaled (written, unused by attn)
    // [76,92)   Kh fp16 [b,h,t,d]
    // [92,108)  Kl fp16 [b,h,t,d] (pre-sparsemax lo; read by sparsemax only)
    // [108,124) Vt fp16 [b,h,d,t]
    char* ws = (char*)d_ws;
    _Float16* xh   = (_Float16*)(ws);
    _Float16* xl   = (_Float16*)(ws + ((size_t)16 << 20));
    _Float16* WhT  = (_Float16*)(ws + ((size_t)32 << 20));
    _Float16* WlT  = (_Float16*)(ws + ((size_t)38 << 20));
    _Float16* Qh_  = (_Float16*)(ws + ((size_t)44 << 20));
    _Float16* Ql_  = (_Float16*)(ws + ((size_t)60 << 20));
    _Float16* Kh_  = (_Float16*)(ws + ((size_t)76 << 20));
    _Float16* Kl_  = (_Float16*)(ws + ((size_t)92 << 20));
    _Float16* Vt_  = (_Float16*)(ws + ((size_t)108 << 20));
    _Float16* Yh   = xh;
    _Float16* Yl   = xl;
    _Float16* WphT = WhT;
    _Float16* WplT = (_Float16*)(ws + ((size_t)34 << 20));

    split_x_kernel<<<(MM * CC) / (256 * 4), 256, 0, stream>>>(x, xh, xl);
    splitT_w_kernel<<<dim3(3 * CC / 64, CC / 64), 256, 0, stream>>>(
        W_attn, WhT, WlT, CC, 3 * CC);
    // QKV GEMM: grid 64 x 12 = 768 blocks
    gemm_ht3_kernel<<<dim3((MM / 128) * (3 * CC / 256)), 512, 0, stream>>>(
        xh, xl, WhT, WlT, b_attn, nullptr,
        Qh_, Ql_, Kh_, Kl_, Vt_, 3 * CC, CC, 3 * CC / 256, 1);
    sparsemax_kernel<<<dim3((NB * NH * TT) / 4), 256, 0, stream>>>(Kh_, Kl_);
    attn_kernel<<<dim3(512), 256, 0, stream>>>(Qh_, Kh_, Vt_, Yh, Yl);
    splitT_w_kernel<<<dim3(CC / 64, CC / 64), 256, 0, stream>>>(
        W_proj, WphT, WplT, CC, CC);
    // proj GEMM: grid 64 x 4 = 256 blocks
    gemm_ht3_kernel<<<dim3((MM / 128) * (CC / 256)), 512, 0, stream>>>(
        Yh, Yl, WphT, WplT, b_proj, out,
        nullptr, nullptr, nullptr, nullptr, nullptr, CC, CC, CC / 256, 0);
}